// Round 1
// baseline (1041.274 us; speedup 1.0000x reference)
//
#include <hip/hip_runtime.h>

#define CN0 16000
#define CN1 12000
#define CN2 6000
#define CH 256
#define COUT 128

// ---------------- embed + fc_input: h0[n][j] = sum_k e[n][k]*Win[k][j] + bin[j]
__global__ __launch_bounds__(256) void embed_fc_kernel(
    const int* __restrict__ x,
    const float* __restrict__ e0, const float* __restrict__ e1, const float* __restrict__ e2,
    const float* __restrict__ Win, const float* __restrict__ bin,
    float* __restrict__ h0)
{
    __shared__ float sE[8][128];
    const int row0 = blockIdx.x * 8;
    const int t = threadIdx.x;
    for (int i = t; i < 8 * 128; i += 256) {
        const int r = i >> 7, k = i & 127;
        const int row = row0 + r;
        float v;
        if (k < 64)      v = e0[x[row * 3 + 0] * 64 + k];
        else if (k < 96) v = e1[x[row * 3 + 1] * 32 + (k - 64)];
        else             v = e2[x[row * 3 + 2] * 32 + (k - 96)];
        sE[r][k] = v;
    }
    __syncthreads();
    const int j = t;            // 0..255 output feature
    float acc[8];
    const float b = bin[j];
#pragma unroll
    for (int r = 0; r < 8; ++r) acc[r] = b;
    for (int k = 0; k < 128; ++k) {
        const float w = Win[k * 256 + j];
#pragma unroll
        for (int r = 0; r < 8; ++r) acc[r] += sE[r][k] * w;
    }
#pragma unroll
    for (int r = 0; r < 8; ++r) h0[(row0 + r) * 256 + j] = acc[r];
}

// ---------------- co-attention aggregation; one block per dst node
// D = feat[idxD[n]], Q = feat[idxQ[n]]  (K rows x 256)
// L[k][m] = <D[k], Q[m]>;  AC = softmax rows;  AS[k][m] = softmax over m of L[m][k]
// CQ = AC@Q ; CD = AS@concat(D,CQ) ; h = concat(Q,CD) [K x 768]
// pooled = avgpool3(h) ; neigh = mean_k ; out = feat[n] + neigh (optional relu)
template <int K>
__global__ __launch_bounds__(256) void coagg_kernel(
    const float* __restrict__ feat,
    const int* __restrict__ idxD, const int* __restrict__ idxQ,
    float* __restrict__ outp, const int relu)
{
    __shared__ float sD[K][256];
    __shared__ float sH[K][768];     // [0,256)=Q, [256,512)=CD0, [512,768)=CD1
    __shared__ float sLp[K * K * 4];
    __shared__ float sL[K * K];
    __shared__ float sAC[K * K];
    __shared__ float sAS[K * K];

    const int n = blockIdx.x;
    const int f = threadIdx.x;       // feature column 0..255
    const int w = f >> 6, lane = f & 63;

    for (int k = 0; k < K; ++k) {
        sD[k][f] = feat[idxD[n * K + k] * CH + f];
        sH[k][f] = feat[idxQ[n * K + k] * CH + f];
    }
    __syncthreads();

    // L via per-wave partial dot + shfl reduce
    for (int k = 0; k < K; ++k) {
        for (int m = 0; m < K; ++m) {
            float v = sD[k][f] * sH[m][f];
#pragma unroll
            for (int o = 32; o > 0; o >>= 1) v += __shfl_xor(v, o, 64);
            if (lane == 0) sLp[(k * K + m) * 4 + w] = v;
        }
    }
    __syncthreads();
    if (f < K * K) sL[f] = sLp[f * 4] + sLp[f * 4 + 1] + sLp[f * 4 + 2] + sLp[f * 4 + 3];
    __syncthreads();

    // softmaxes (tiny, serial over K)
    if (f < K) {                      // AC row f
        const int k = f;
        float mx = -1e30f;
        for (int m = 0; m < K; ++m) mx = fmaxf(mx, sL[k * K + m]);
        float s = 0.f, e[K];
        for (int m = 0; m < K; ++m) { e[m] = __expf(sL[k * K + m] - mx); s += e[m]; }
        const float inv = 1.f / s;
        for (int m = 0; m < K; ++m) sAC[k * K + m] = e[m] * inv;
    } else if (f >= 64 && f < 64 + K) {  // AS row c = softmax of column c of L
        const int c = f - 64;
        float mx = -1e30f;
        for (int m = 0; m < K; ++m) mx = fmaxf(mx, sL[m * K + c]);
        float s = 0.f, e[K];
        for (int m = 0; m < K; ++m) { e[m] = __expf(sL[m * K + c] - mx); s += e[m]; }
        const float inv = 1.f / s;
        for (int m = 0; m < K; ++m) sAS[c * K + m] = e[m] * inv;
    }
    __syncthreads();

    // CQ kept per-thread in registers (thread f owns column f)
    float cq[K];
#pragma unroll
    for (int k = 0; k < K; ++k) {
        float a = 0.f;
        for (int m = 0; m < K; ++m) a += sAC[k * K + m] * sH[m][f];
        cq[k] = a;
    }
    // CD
#pragma unroll
    for (int k = 0; k < K; ++k) {
        float c0 = 0.f, c1 = 0.f;
        for (int m = 0; m < K; ++m) {
            const float a = sAS[k * K + m];
            c0 += a * sD[m][f];
            c1 += a * cq[m];
        }
        sH[k][256 + f] = c0;
        sH[k][512 + f] = c1;
    }
    __syncthreads();

    // pool3 over features + mean over K + residual
    float acc = 0.f;
    for (int k = 0; k < K; ++k)
        acc += sH[k][3 * f] + sH[k][3 * f + 1] + sH[k][3 * f + 2];
    float v = feat[n * CH + f] + acc * (1.0f / (3.0f * K));
    if (relu) v = fmaxf(v, 0.f);
    outp[n * CH + f] = v;
}

// ---------------- h2[6000x256] @ Wout[256x128] + bout
__global__ __launch_bounds__(128) void fc_out_kernel(
    const float* __restrict__ h2, const float* __restrict__ Wout,
    const float* __restrict__ bout, float* __restrict__ outp)
{
    __shared__ float sIn[8][256];
    const int row0 = blockIdx.x * 8;
    const int t = threadIdx.x;   // 0..127
    for (int i = t; i < 8 * 256; i += 128) sIn[i >> 8][i & 255] = h2[row0 * 256 + i];
    __syncthreads();
    float acc[8];
    const float b = bout[t];
#pragma unroll
    for (int r = 0; r < 8; ++r) acc[r] = b;
    for (int k = 0; k < 256; ++k) {
        const float w = Wout[k * 128 + t];
#pragma unroll
        for (int r = 0; r < 8; ++r) acc[r] += sIn[r][k] * w;
    }
#pragma unroll
    for (int r = 0; r < 8; ++r) outp[(row0 + r) * 128 + t] = acc[r];
}

// ---------------- out = in[6000x128] @ W[128x128]
__global__ __launch_bounds__(128) void mm128_kernel(
    const float* __restrict__ inp, const float* __restrict__ W,
    float* __restrict__ outp)
{
    __shared__ float sIn[8][128];
    const int row0 = blockIdx.x * 8;
    const int t = threadIdx.x;
    for (int i = t; i < 8 * 128; i += 128) sIn[i >> 7][i & 127] = inp[row0 * 128 + i];
    __syncthreads();
    float acc[8];
#pragma unroll
    for (int r = 0; r < 8; ++r) acc[r] = 0.f;
    for (int k = 0; k < 128; ++k) {
        const float w = W[k * 128 + t];
#pragma unroll
        for (int r = 0; r < 8; ++r) acc[r] += sIn[r][k] * w;
    }
#pragma unroll
    for (int r = 0; r < 8; ++r) outp[(row0 + r) * 128 + t] = acc[r];
}

// ---------------- z2 = c0*base1 + c1*base2 + c2*(mm_in @ W)
__global__ __launch_bounds__(128) void integ2_kernel(
    const float* __restrict__ mm_in, const float* __restrict__ W,
    const float* __restrict__ base1, const float* __restrict__ base2,
    const float* __restrict__ a1p, const float* __restrict__ a2p,
    const float* __restrict__ b2p, float* __restrict__ outp)
{
    const float a1 = *a1p, a2 = *a2p, b2 = *b2p;
    const float c0 = 1.f - a2 - b2;
    const float c1 = a2 + b2 * (1.f - a1);
    const float c2 = b2 * a1;

    __shared__ float sIn[8][128];
    const int row0 = blockIdx.x * 8;
    const int t = threadIdx.x;
    for (int i = t; i < 8 * 128; i += 128) sIn[i >> 7][i & 127] = mm_in[row0 * 128 + i];
    __syncthreads();
    float acc[8];
#pragma unroll
    for (int r = 0; r < 8; ++r) acc[r] = 0.f;
    for (int k = 0; k < 128; ++k) {
        const float w = W[k * 128 + t];
#pragma unroll
        for (int r = 0; r < 8; ++r) acc[r] += sIn[r][k] * w;
    }
#pragma unroll
    for (int r = 0; r < 8; ++r) {
        const int idx = (row0 + r) * 128 + t;
        outp[idx] = c0 * base1[idx] + c1 * base2[idx] + c2 * acc[r];
    }
}

extern "C" void kernel_launch(void* const* d_in, const int* in_sizes, int n_in,
                              void* d_out, int out_size, void* d_ws, size_t ws_size,
                              hipStream_t stream)
{
    const int* x        = (const int*)d_in[0];
    const int* idx_sim0 = (const int*)d_in[1];
    const int* idx_cor0 = (const int*)d_in[2];
    const int* idx_sim1 = (const int*)d_in[3];
    const int* idx_cor1 = (const int*)d_in[4];
    const float* Ws2c = (const float*)d_in[19];
    const float* Wc2s = (const float*)d_in[20];
    const float* a1 = (const float*)d_in[21];
    const float* a2 = (const float*)d_in[22];
    const float* b2 = (const float*)d_in[23];

    float* ws   = (float*)d_ws;
    float* A    = ws;                 // h0: 16000*256
    float* B    = A + 16000 * 256;    // h1: 12000*256
    float* C    = B + 12000 * 256;    // h2:  6000*256
    float* simO = C + 6000 * 256;     // 6000*128
    float* corO = simO + 6000 * 128;
    float* P    = corO + 6000 * 128;  // cor @ Wc2s
    float* S    = P + 6000 * 128;     // sim @ Ws2c

    float* outSim = (float*)d_out;
    float* outCor = outSim + 6000 * 128;

    for (int b = 0; b < 2; ++b) {
        const int base = 5 + b * 7;
        const float* e0   = (const float*)d_in[base + 0];
        const float* e1   = (const float*)d_in[base + 1];
        const float* e2   = (const float*)d_in[base + 2];
        const float* Win  = (const float*)d_in[base + 3];
        const float* bin  = (const float*)d_in[base + 4];
        const float* Wout = (const float*)d_in[base + 5];
        const float* bout = (const float*)d_in[base + 6];
        // mode 'sim' (b==0): D = feat[idx_cor], Q = feat[idx_sim]; 'cor': swapped
        const int* iD0 = (b == 0) ? idx_cor0 : idx_sim0;
        const int* iQ0 = (b == 0) ? idx_sim0 : idx_cor0;
        const int* iD1 = (b == 0) ? idx_cor1 : idx_sim1;
        const int* iQ1 = (b == 0) ? idx_sim1 : idx_cor1;
        float* branchOut = (b == 0) ? simO : corO;

        embed_fc_kernel<<<2000, 256, 0, stream>>>(x, e0, e1, e2, Win, bin, A);
        coagg_kernel<10><<<12000, 256, 0, stream>>>(A, iD0, iQ0, B, 1);
        coagg_kernel<5><<<6000, 256, 0, stream>>>(B, iD1, iQ1, C, 0);
        fc_out_kernel<<<750, 128, 0, stream>>>(C, Wout, bout, branchOut);
    }

    // P = cor@Wc2s ; S = sim@Ws2c
    mm128_kernel<<<750, 128, 0, stream>>>(corO, Wc2s, P);
    mm128_kernel<<<750, 128, 0, stream>>>(simO, Ws2c, S);
    // z2sim = c0*sim + c1*P + c2*(S@Wc2s) ; z2cor = c0*cor + c1*S + c2*(P@Ws2c)
    integ2_kernel<<<750, 128, 0, stream>>>(S, Wc2s, simO, P, a1, a2, b2, outSim);
    integ2_kernel<<<750, 128, 0, stream>>>(P, Ws2c, corO, S, a1, a2, b2, outCor);
}

// Round 2
// 424.658 us; speedup vs baseline: 2.4520x; 2.4520x over previous
//
#include <hip/hip_runtime.h>

#define CN0 16000
#define CN1 12000
#define CN2 6000
#define CH 256
#define COUT 128

// ---------------- embed + fc_input: h0[n][j] = sum_k e[n][k]*Win[k][j] + bin[j]
__global__ __launch_bounds__(256) void embed_fc_kernel(
    const int* __restrict__ x,
    const float* __restrict__ e0, const float* __restrict__ e1, const float* __restrict__ e2,
    const float* __restrict__ Win, const float* __restrict__ bin,
    float* __restrict__ h0)
{
    __shared__ float sE[8][128];
    const int row0 = blockIdx.x * 8;
    const int t = threadIdx.x;
    for (int i = t; i < 8 * 128; i += 256) {
        const int r = i >> 7, k = i & 127;
        const int row = row0 + r;
        float v;
        if (k < 64)      v = e0[x[row * 3 + 0] * 64 + k];
        else if (k < 96) v = e1[x[row * 3 + 1] * 32 + (k - 64)];
        else             v = e2[x[row * 3 + 2] * 32 + (k - 96)];
        sE[r][k] = v;
    }
    __syncthreads();
    const int j = t;            // 0..255 output feature
    float acc[8];
    const float b = bin[j];
#pragma unroll
    for (int r = 0; r < 8; ++r) acc[r] = b;
    for (int k = 0; k < 128; ++k) {
        const float w = Win[k * 256 + j];
#pragma unroll
        for (int r = 0; r < 8; ++r) acc[r] += sE[r][k] * w;
    }
#pragma unroll
    for (int r = 0; r < 8; ++r) h0[(row0 + r) * 256 + j] = acc[r];
}

// ---------------- co-attention aggregation; one block per dst node
// L[k][m] = <D[k],Q[m]>; AC=row-softmax(L); AS[c][m]=softmax_m of L[m][c]
// Linearity: sum_k h[k] = [ sum_k Q[k] | sum_m w[m]D[m] | sum_j u[j]Q[j] ]
//   where w = colsum(AS), u = AC^T w.  Then pool3 + mean_k + residual.
template <int K>
__global__ __launch_bounds__(256) void coagg_kernel(
    const float* __restrict__ feat,
    const int* __restrict__ idxD, const int* __restrict__ idxQ,
    float* __restrict__ outp, const int relu)
{
    __shared__ float sD[K][256];
    __shared__ float sQ[K][256];
    __shared__ float sL[K][K];
    __shared__ float sAC[K][K];
    __shared__ float sAS[K][K];
    __shared__ float sw[K];
    __shared__ float su[K];
    __shared__ float sHsum[768];

    const int n = blockIdx.x;
    const int t = threadIdx.x;
    const int w = t >> 6, lane = t & 63;

    // gather D,Q rows (float4, coalesced per row)
    {
        const float4* fp = (const float4*)feat;
        for (int i = t; i < K * 64; i += 256) {
            const int row = i >> 6, c = i & 63;
            ((float4*)&sD[row][0])[c] = fp[(size_t)idxD[n * K + row] * 64 + c];
            ((float4*)&sQ[row][0])[c] = fp[(size_t)idxQ[n * K + row] * 64 + c];
        }
    }
    __syncthreads();

    // L: each wave owns a subset of (k,m) pairs; lane dots a float4 slice
    for (int p = w; p < K * K; p += 4) {
        const int k = p / K, m = p % K;
        const float4 d = ((const float4*)&sD[k][0])[lane];
        const float4 q = ((const float4*)&sQ[m][0])[lane];
        float v = d.x * q.x + d.y * q.y + d.z * q.z + d.w * q.w;
#pragma unroll
        for (int o = 32; o; o >>= 1) v += __shfl_xor(v, o, 64);
        if (lane == 0) sL[k][m] = v;
    }
    __syncthreads();

    // softmaxes (tiny, serial over K)
    if (t < K) {                      // AC row t
        const int k = t;
        float mx = -1e30f;
        for (int m = 0; m < K; ++m) mx = fmaxf(mx, sL[k][m]);
        float s = 0.f, e[K];
        for (int m = 0; m < K; ++m) { e[m] = __expf(sL[k][m] - mx); s += e[m]; }
        const float inv = 1.f / s;
        for (int m = 0; m < K; ++m) sAC[k][m] = e[m] * inv;
    } else if (t >= 64 && t < 64 + K) {  // AS row c (softmax of column c of L)
        const int c = t - 64;
        float mx = -1e30f;
        for (int m = 0; m < K; ++m) mx = fmaxf(mx, sL[m][c]);
        float s = 0.f, e[K];
        for (int m = 0; m < K; ++m) { e[m] = __expf(sL[m][c] - mx); s += e[m]; }
        const float inv = 1.f / s;
        for (int m = 0; m < K; ++m) sAS[c][m] = e[m] * inv;
    }
    __syncthreads();

    if (t < K) {                      // w[m] = colsum of AS, m = t
        float s = 0.f;
        for (int k = 0; k < K; ++k) s += sAS[k][t];
        sw[t] = s;
    }
    __syncthreads();
    if (t < K) {                      // u[j] = sum_m w[m]*AC[m][j], j = t
        float s = 0.f;
        for (int m = 0; m < K; ++m) s += sw[m] * sAC[m][t];
        su[t] = s;
    }
    __syncthreads();

    // three K-weighted row sums; thread t owns feature column t
    float hs0 = 0.f, hs1 = 0.f, hs2 = 0.f;
#pragma unroll
    for (int k = 0; k < K; ++k) {
        const float qv = sQ[k][t];
        hs0 += qv;
        hs1 += sw[k] * sD[k][t];
        hs2 += su[k] * qv;
    }
    sHsum[t]       = hs0;
    sHsum[256 + t] = hs1;
    sHsum[512 + t] = hs2;
    __syncthreads();

    const float acc = sHsum[3 * t] + sHsum[3 * t + 1] + sHsum[3 * t + 2];
    float v = feat[(size_t)n * CH + t] + acc * (1.0f / (3.0f * K));
    if (relu) v = fmaxf(v, 0.f);
    outp[(size_t)n * CH + t] = v;
}

// ---------------- h2[6000x256] @ Wout[256x128] + bout
__global__ __launch_bounds__(128) void fc_out_kernel(
    const float* __restrict__ h2, const float* __restrict__ Wout,
    const float* __restrict__ bout, float* __restrict__ outp)
{
    __shared__ float sIn[8][256];
    const int row0 = blockIdx.x * 8;
    const int t = threadIdx.x;   // 0..127
    for (int i = t; i < 8 * 256; i += 128) sIn[i >> 8][i & 255] = h2[row0 * 256 + i];
    __syncthreads();
    float acc[8];
    const float b = bout[t];
#pragma unroll
    for (int r = 0; r < 8; ++r) acc[r] = b;
    for (int k = 0; k < 256; ++k) {
        const float w = Wout[k * 128 + t];
#pragma unroll
        for (int r = 0; r < 8; ++r) acc[r] += sIn[r][k] * w;
    }
#pragma unroll
    for (int r = 0; r < 8; ++r) outp[(row0 + r) * 128 + t] = acc[r];
}

// ---------------- out = in[6000x128] @ W[128x128]
__global__ __launch_bounds__(128) void mm128_kernel(
    const float* __restrict__ inp, const float* __restrict__ W,
    float* __restrict__ outp)
{
    __shared__ float sIn[8][128];
    const int row0 = blockIdx.x * 8;
    const int t = threadIdx.x;
    for (int i = t; i < 8 * 128; i += 128) sIn[i >> 7][i & 127] = inp[row0 * 128 + i];
    __syncthreads();
    float acc[8];
#pragma unroll
    for (int r = 0; r < 8; ++r) acc[r] = 0.f;
    for (int k = 0; k < 128; ++k) {
        const float w = W[k * 128 + t];
#pragma unroll
        for (int r = 0; r < 8; ++r) acc[r] += sIn[r][k] * w;
    }
#pragma unroll
    for (int r = 0; r < 8; ++r) outp[(row0 + r) * 128 + t] = acc[r];
}

// ---------------- z2 = c0*base1 + c1*base2 + c2*(mm_in @ W)
__global__ __launch_bounds__(128) void integ2_kernel(
    const float* __restrict__ mm_in, const float* __restrict__ W,
    const float* __restrict__ base1, const float* __restrict__ base2,
    const float* __restrict__ a1p, const float* __restrict__ a2p,
    const float* __restrict__ b2p, float* __restrict__ outp)
{
    const float a1 = *a1p, a2 = *a2p, b2 = *b2p;
    const float c0 = 1.f - a2 - b2;
    const float c1 = a2 + b2 * (1.f - a1);
    const float c2 = b2 * a1;

    __shared__ float sIn[8][128];
    const int row0 = blockIdx.x * 8;
    const int t = threadIdx.x;
    for (int i = t; i < 8 * 128; i += 128) sIn[i >> 7][i & 127] = mm_in[row0 * 128 + i];
    __syncthreads();
    float acc[8];
#pragma unroll
    for (int r = 0; r < 8; ++r) acc[r] = 0.f;
    for (int k = 0; k < 128; ++k) {
        const float w = W[k * 128 + t];
#pragma unroll
        for (int r = 0; r < 8; ++r) acc[r] += sIn[r][k] * w;
    }
#pragma unroll
    for (int r = 0; r < 8; ++r) {
        const int idx = (row0 + r) * 128 + t;
        outp[idx] = c0 * base1[idx] + c1 * base2[idx] + c2 * acc[r];
    }
}

extern "C" void kernel_launch(void* const* d_in, const int* in_sizes, int n_in,
                              void* d_out, int out_size, void* d_ws, size_t ws_size,
                              hipStream_t stream)
{
    const int* x        = (const int*)d_in[0];
    const int* idx_sim0 = (const int*)d_in[1];
    const int* idx_cor0 = (const int*)d_in[2];
    const int* idx_sim1 = (const int*)d_in[3];
    const int* idx_cor1 = (const int*)d_in[4];
    const float* Ws2c = (const float*)d_in[19];
    const float* Wc2s = (const float*)d_in[20];
    const float* a1 = (const float*)d_in[21];
    const float* a2 = (const float*)d_in[22];
    const float* b2 = (const float*)d_in[23];

    float* ws   = (float*)d_ws;
    float* A    = ws;                 // h0: 16000*256
    float* B    = A + 16000 * 256;    // h1: 12000*256
    float* C    = B + 12000 * 256;    // h2:  6000*256
    float* simO = C + 6000 * 256;     // 6000*128
    float* corO = simO + 6000 * 128;
    float* P    = corO + 6000 * 128;  // cor @ Wc2s
    float* S    = P + 6000 * 128;     // sim @ Ws2c

    float* outSim = (float*)d_out;
    float* outCor = outSim + 6000 * 128;

    for (int b = 0; b < 2; ++b) {
        const int base = 5 + b * 7;
        const float* e0   = (const float*)d_in[base + 0];
        const float* e1   = (const float*)d_in[base + 1];
        const float* e2   = (const float*)d_in[base + 2];
        const float* Win  = (const float*)d_in[base + 3];
        const float* bin  = (const float*)d_in[base + 4];
        const float* Wout = (const float*)d_in[base + 5];
        const float* bout = (const float*)d_in[base + 6];
        // mode 'sim' (b==0): D = feat[idx_cor], Q = feat[idx_sim]; 'cor': swapped
        const int* iD0 = (b == 0) ? idx_cor0 : idx_sim0;
        const int* iQ0 = (b == 0) ? idx_sim0 : idx_cor0;
        const int* iD1 = (b == 0) ? idx_cor1 : idx_sim1;
        const int* iQ1 = (b == 0) ? idx_sim1 : idx_cor1;
        float* branchOut = (b == 0) ? simO : corO;

        embed_fc_kernel<<<2000, 256, 0, stream>>>(x, e0, e1, e2, Win, bin, A);
        coagg_kernel<10><<<12000, 256, 0, stream>>>(A, iD0, iQ0, B, 1);
        coagg_kernel<5><<<6000, 256, 0, stream>>>(B, iD1, iQ1, C, 0);
        fc_out_kernel<<<750, 128, 0, stream>>>(C, Wout, bout, branchOut);
    }

    // P = cor@Wc2s ; S = sim@Ws2c
    mm128_kernel<<<750, 128, 0, stream>>>(corO, Wc2s, P);
    mm128_kernel<<<750, 128, 0, stream>>>(simO, Ws2c, S);
    // z2sim = c0*sim + c1*P + c2*(S@Wc2s) ; z2cor = c0*cor + c1*S + c2*(P@Ws2c)
    integ2_kernel<<<750, 128, 0, stream>>>(S, Wc2s, simO, P, a1, a2, b2, outSim);
    integ2_kernel<<<750, 128, 0, stream>>>(P, Ws2c, corO, S, a1, a2, b2, outCor);
}

// Round 4
// 282.106 us; speedup vs baseline: 3.6911x; 1.5053x over previous
//
#include <hip/hip_runtime.h>

#define CH 256

// ---------------- embed + fc_input (dual-branch): 16 rows/block
__global__ __launch_bounds__(256) void embed_fc_kernel(
    const int* __restrict__ x,
    const float* __restrict__ e0a, const float* __restrict__ e1a, const float* __restrict__ e2a,
    const float* __restrict__ Wina, const float* __restrict__ bina, float* __restrict__ h0a,
    const float* __restrict__ e0b, const float* __restrict__ e1b, const float* __restrict__ e2b,
    const float* __restrict__ Winb, const float* __restrict__ binb, float* __restrict__ h0b,
    const int blocksPer)
{
    __shared__ float sE[16][128];
    int bid = blockIdx.x;
    const float *e0, *e1, *e2, *Win, *bin;
    float* h0;
    if (bid < blocksPer) { e0 = e0a; e1 = e1a; e2 = e2a; Win = Wina; bin = bina; h0 = h0a; }
    else { bid -= blocksPer; e0 = e0b; e1 = e1b; e2 = e2b; Win = Winb; bin = binb; h0 = h0b; }

    const int row0 = bid * 16;
    const int t = threadIdx.x;
    for (int i = t; i < 16 * 128; i += 256) {
        const int r = i >> 7, k = i & 127;
        const int row = row0 + r;
        float v;
        if (k < 64)      v = e0[x[row * 3 + 0] * 64 + k];
        else if (k < 96) v = e1[x[row * 3 + 1] * 32 + (k - 64)];
        else             v = e2[x[row * 3 + 2] * 32 + (k - 96)];
        sE[r][k] = v;
    }
    __syncthreads();
    const int j = t;
    float acc[16];
    const float b = bin[j];
#pragma unroll
    for (int r = 0; r < 16; ++r) acc[r] = b;
    for (int k = 0; k < 128; ++k) {
        const float wv = Win[k * 256 + j];
#pragma unroll
        for (int r = 0; r < 16; ++r) acc[r] += sE[r][k] * wv;
    }
#pragma unroll
    for (int r = 0; r < 16; ++r) h0[(size_t)(row0 + r) * 256 + j] = acc[r];
}

// ---------------- co-attention aggregation (dual-branch); one block per dst node
// L[k][m]=<D[k],Q[m]>; AC=row-softmax; AS[c][m]=softmax_m L[m][c]
// sum_k h[k] = [ sum Q | sum_m w_m D_m | sum_j u_j Q_j ], w=colsum(AS), u=AC^T w
template <int K>
__global__ __launch_bounds__(256) void coagg_kernel(
    const float* __restrict__ fa, const int* __restrict__ iDa, const int* __restrict__ iQa,
    float* __restrict__ oa,
    const float* __restrict__ fb, const int* __restrict__ iDb, const int* __restrict__ iQb,
    float* __restrict__ ob,
    const int nPer, const int relu)
{
    __shared__ __align__(16) float sD[K][256];
    __shared__ __align__(16) float sQ[K][256];
    __shared__ float sL[K][K];
    __shared__ float sAC[K][K];
    __shared__ float sAS[K][K];
    __shared__ float sw_[K], su_[K];
    __shared__ __align__(16) float sHsum[768];

    int n = blockIdx.x;
    const float* feat; const int* idxD; const int* idxQ; float* outp;
    if (n < nPer) { feat = fa; idxD = iDa; idxQ = iQa; outp = oa; }
    else { n -= nPer; feat = fb; idxD = iDb; idxQ = iQb; outp = ob; }

    const int t = threadIdx.x;
    const int w = t >> 6, lane = t & 63;

    // gather D,Q rows into LDS (coalesced b128 per row)
    {
        const float4* fp = (const float4*)feat;
        for (int i = t; i < K * 64; i += 256) {
            const int row = i >> 6, c = i & 63;
            ((float4*)&sD[row][0])[c] = fp[(size_t)idxD[n * K + row] * 64 + c];
            ((float4*)&sQ[row][0])[c] = fp[(size_t)idxQ[n * K + row] * 64 + c];
        }
    }
    const float resid = feat[(size_t)n * CH + t];   // prefetch residual (used at the end)
    __syncthreads();

    // all Q rows into registers (per wave; lane holds float4 slice; static indices only)
    float4 Q[K];
#pragma unroll
    for (int m = 0; m < K; ++m) Q[m] = ((const float4*)&sQ[m][0])[lane];

    // L-phase: wave w owns rows k = w + 4*kk; 2-pair exchange reduction:
    //  after one xor-32 exchange, lanes 0-31 hold pair m0 2-lane partials,
    //  lanes 32-63 hold pair m0+1; xor 16/8/4/2/1 completes each half.
#pragma unroll
    for (int kk = 0; kk < (K + 3) / 4; ++kk) {
        const int k = w + kk * 4;
        if (k < K) {                          // wave-uniform branch
            const float4 d = ((const float4*)&sD[k][0])[lane];
#pragma unroll
            for (int m0 = 0; m0 < K; m0 += 2) {
                const float4 q0 = Q[m0];
                float s0 = d.x * q0.x + d.y * q0.y + d.z * q0.z + d.w * q0.w;
                float s1 = 0.f;
                if (m0 + 1 < K) {             // compile-time after unroll
                    const float4 q1 = Q[m0 + 1];
                    s1 = d.x * q1.x + d.y * q1.y + d.z * q1.z + d.w * q1.w;
                }
                float mine  = (lane < 32) ? s0 : s1;
                float other = (lane < 32) ? s1 : s0;
                mine += __shfl_xor(other, 32, 64);
                mine += __shfl_xor(mine, 16, 64);
                mine += __shfl_xor(mine, 8, 64);
                mine += __shfl_xor(mine, 4, 64);
                mine += __shfl_xor(mine, 2, 64);
                mine += __shfl_xor(mine, 1, 64);
                if (lane == 0) sL[k][m0] = mine;
                if (lane == 32 && m0 + 1 < K) sL[k][m0 + 1] = mine;
            }
        }
    }
    __syncthreads();

    // stage A: softmaxes (wave 0; two disjoint lane groups; read sL only)
    if (w == 0) {
        if (lane < K) {                       // AC row = lane
            float e_[K], mx = -1e30f;
#pragma unroll
            for (int m = 0; m < K; ++m) mx = fmaxf(mx, sL[lane][m]);
            float ssum = 0.f;
#pragma unroll
            for (int m = 0; m < K; ++m) { e_[m] = __expf(sL[lane][m] - mx); ssum += e_[m]; }
            const float inv = 1.f / ssum;
#pragma unroll
            for (int m = 0; m < K; ++m) sAC[lane][m] = e_[m] * inv;
        }
        const int c = lane - 16;
        if (c >= 0 && c < K) {                // AS row c = softmax of column c of L
            float e_[K], mx = -1e30f;
#pragma unroll
            for (int m = 0; m < K; ++m) mx = fmaxf(mx, sL[m][c]);
            float ssum = 0.f;
#pragma unroll
            for (int m = 0; m < K; ++m) { e_[m] = __expf(sL[m][c] - mx); ssum += e_[m]; }
            const float inv = 1.f / ssum;
#pragma unroll
            for (int m = 0; m < K; ++m) sAS[c][m] = e_[m] * inv;
        }
    }
    __syncthreads();

    // stage B: w[m] = colsum(AS)
    if (t < K) {
        float s = 0.f;
#pragma unroll
        for (int k2 = 0; k2 < K; ++k2) s += sAS[k2][t];
        sw_[t] = s;
    }
    __syncthreads();

    // stage C: u[j] = sum_m w[m]*AC[m][j]
    if (t < K) {
        float s = 0.f;
#pragma unroll
        for (int m = 0; m < K; ++m) s += sw_[m] * sAC[m][t];
        su_[t] = s;
    }
    __syncthreads();

    // stage D: weighted row sums (wave 0; lane owns float4 feature slice)
    if (w == 0) {
        float4 h0v = make_float4(0.f, 0.f, 0.f, 0.f);
        float4 h1v = make_float4(0.f, 0.f, 0.f, 0.f);
        float4 h2v = make_float4(0.f, 0.f, 0.f, 0.f);
#pragma unroll
        for (int kx = 0; kx < K; ++kx) {
            const float wk = sw_[kx], uk = su_[kx];
            const float4 q = Q[kx];
            const float4 d = ((const float4*)&sD[kx][0])[lane];
            h0v.x += q.x;      h0v.y += q.y;      h0v.z += q.z;      h0v.w += q.w;
            h1v.x += wk * d.x; h1v.y += wk * d.y; h1v.z += wk * d.z; h1v.w += wk * d.w;
            h2v.x += uk * q.x; h2v.y += uk * q.y; h2v.z += uk * q.z; h2v.w += uk * q.w;
        }
        ((float4*)&sHsum[0])[lane]   = h0v;
        ((float4*)&sHsum[256])[lane] = h1v;
        ((float4*)&sHsum[512])[lane] = h2v;
    }
    __syncthreads();

    // stage E: pool3 + mean_k + residual
    const float acc = sHsum[3 * t] + sHsum[3 * t + 1] + sHsum[3 * t + 2];
    float v = resid + acc * (1.0f / (3.0f * K));
    if (relu) v = fmaxf(v, 0.f);
    outp[(size_t)n * CH + t] = v;
}

// ---------------- h2[.x256] @ Wout[256x128] + bout (dual-branch)
__global__ __launch_bounds__(128) void fc_out_kernel(
    const float* __restrict__ h2a, const float* __restrict__ Wouta,
    const float* __restrict__ bouta, float* __restrict__ oa,
    const float* __restrict__ h2b, const float* __restrict__ Woutb,
    const float* __restrict__ boutb, float* __restrict__ ob,
    const int blocksPer)
{
    __shared__ float sIn[8][256];
    int bid = blockIdx.x;
    const float *h2, *Wout, *bout; float* outp;
    if (bid < blocksPer) { h2 = h2a; Wout = Wouta; bout = bouta; outp = oa; }
    else { bid -= blocksPer; h2 = h2b; Wout = Woutb; bout = boutb; outp = ob; }

    const int row0 = bid * 8;
    const int t = threadIdx.x;
    for (int i = t; i < 8 * 256; i += 128) sIn[i >> 8][i & 255] = h2[(size_t)row0 * 256 + i];
    __syncthreads();
    float acc[8];
    const float b = bout[t];
#pragma unroll
    for (int r = 0; r < 8; ++r) acc[r] = b;
    for (int k = 0; k < 256; ++k) {
        const float wv = Wout[k * 128 + t];
#pragma unroll
        for (int r = 0; r < 8; ++r) acc[r] += sIn[r][k] * wv;
    }
#pragma unroll
    for (int r = 0; r < 8; ++r) outp[(size_t)(row0 + r) * 128 + t] = acc[r];
}

// ---------------- out = in[.x128] @ W[128x128] (dual)
__global__ __launch_bounds__(128) void mm128_kernel(
    const float* __restrict__ ina, const float* __restrict__ Wa, float* __restrict__ oa,
    const float* __restrict__ inb, const float* __restrict__ Wb, float* __restrict__ ob,
    const int blocksPer)
{
    __shared__ float sIn[8][128];
    int bid = blockIdx.x;
    const float *inp, *W; float* outp;
    if (bid < blocksPer) { inp = ina; W = Wa; outp = oa; }
    else { bid -= blocksPer; inp = inb; W = Wb; outp = ob; }

    const int row0 = bid * 8;
    const int t = threadIdx.x;
    for (int i = t; i < 8 * 128; i += 128) sIn[i >> 7][i & 127] = inp[(size_t)row0 * 128 + i];
    __syncthreads();
    float acc[8];
#pragma unroll
    for (int r = 0; r < 8; ++r) acc[r] = 0.f;
    for (int k = 0; k < 128; ++k) {
        const float wv = W[k * 128 + t];
#pragma unroll
        for (int r = 0; r < 8; ++r) acc[r] += sIn[r][k] * wv;
    }
#pragma unroll
    for (int r = 0; r < 8; ++r) outp[(size_t)(row0 + r) * 128 + t] = acc[r];
}

// ---------------- z2 = c0*base1 + c1*base2 + c2*(mm_in @ W)   (dual)
__global__ __launch_bounds__(128) void integ2_kernel(
    const float* __restrict__ mma, const float* __restrict__ Wa,
    const float* __restrict__ b1a, const float* __restrict__ b2a, float* __restrict__ oa,
    const float* __restrict__ mmb, const float* __restrict__ Wb,
    const float* __restrict__ b1b, const float* __restrict__ b2b, float* __restrict__ ob,
    const int blocksPer,
    const float* __restrict__ a1p, const float* __restrict__ a2p, const float* __restrict__ b2p)
{
    const float a1 = *a1p, a2 = *a2p, b2 = *b2p;
    const float c0 = 1.f - a2 - b2;
    const float c1 = a2 + b2 * (1.f - a1);
    const float c2 = b2 * a1;

    __shared__ float sIn[8][128];
    int bid = blockIdx.x;
    const float *mm_in, *W, *base1, *base2; float* outp;
    if (bid < blocksPer) { mm_in = mma; W = Wa; base1 = b1a; base2 = b2a; outp = oa; }
    else { bid -= blocksPer; mm_in = mmb; W = Wb; base1 = b1b; base2 = b2b; outp = ob; }

    const int row0 = bid * 8;
    const int t = threadIdx.x;
    for (int i = t; i < 8 * 128; i += 128) sIn[i >> 7][i & 127] = mm_in[(size_t)row0 * 128 + i];
    __syncthreads();
    float acc[8];
#pragma unroll
    for (int r = 0; r < 8; ++r) acc[r] = 0.f;
    for (int k = 0; k < 128; ++k) {
        const float wv = W[k * 128 + t];
#pragma unroll
        for (int r = 0; r < 8; ++r) acc[r] += sIn[r][k] * wv;
    }
#pragma unroll
    for (int r = 0; r < 8; ++r) {
        const size_t idx = (size_t)(row0 + r) * 128 + t;
        outp[idx] = c0 * base1[idx] + c1 * base2[idx] + c2 * acc[r];
    }
}

extern "C" void kernel_launch(void* const* d_in, const int* in_sizes, int n_in,
                              void* d_out, int out_size, void* d_ws, size_t ws_size,
                              hipStream_t stream)
{
    const int* x        = (const int*)d_in[0];
    const int* idx_sim0 = (const int*)d_in[1];
    const int* idx_cor0 = (const int*)d_in[2];
    const int* idx_sim1 = (const int*)d_in[3];
    const int* idx_cor1 = (const int*)d_in[4];
    const float* e0s  = (const float*)d_in[5];
    const float* e1s  = (const float*)d_in[6];
    const float* e2s  = (const float*)d_in[7];
    const float* Wins = (const float*)d_in[8];
    const float* bins = (const float*)d_in[9];
    const float* Wouts= (const float*)d_in[10];
    const float* bouts= (const float*)d_in[11];
    const float* e0c  = (const float*)d_in[12];
    const float* e1c  = (const float*)d_in[13];
    const float* e2c  = (const float*)d_in[14];
    const float* Winc = (const float*)d_in[15];
    const float* binc = (const float*)d_in[16];
    const float* Woutc= (const float*)d_in[17];
    const float* boutc= (const float*)d_in[18];
    const float* Ws2c = (const float*)d_in[19];
    const float* Wc2s = (const float*)d_in[20];
    const float* a1 = (const float*)d_in[21];
    const float* a2 = (const float*)d_in[22];
    const float* b2 = (const float*)d_in[23];

    float* outSim = (float*)d_out;
    float* outCor = outSim + 6000 * 128;

    float* ws = (float*)d_ws;
    const size_t needMerged = (size_t)(2 * 16000 * 256 + 2 * 12000 * 256 + 2 * 6000 * 256 + 4 * 6000 * 128) * 4;
    const bool merged = ws_size >= needMerged;

    if (merged) {
        float* A0 = ws;
        float* A1 = A0 + 16000 * 256;
        float* B0 = A1 + 16000 * 256;
        float* B1 = B0 + 12000 * 256;
        float* C0 = B1 + 12000 * 256;
        float* C1 = C0 + 6000 * 256;
        float* simO = C1 + 6000 * 256;
        float* corO = simO + 6000 * 128;
        float* P    = corO + 6000 * 128;
        float* S    = P + 6000 * 128;

        embed_fc_kernel<<<2000, 256, 0, stream>>>(x,
            e0s, e1s, e2s, Wins, bins, A0,
            e0c, e1c, e2c, Winc, binc, A1, 1000);
        // sim: D=feat[idx_cor], Q=feat[idx_sim]; cor: swapped
        coagg_kernel<10><<<24000, 256, 0, stream>>>(
            A0, idx_cor0, idx_sim0, B0,
            A1, idx_sim0, idx_cor0, B1, 12000, 1);
        coagg_kernel<5><<<12000, 256, 0, stream>>>(
            B0, idx_cor1, idx_sim1, C0,
            B1, idx_sim1, idx_cor1, C1, 6000, 0);
        fc_out_kernel<<<1500, 128, 0, stream>>>(
            C0, Wouts, bouts, simO,
            C1, Woutc, boutc, corO, 750);
        // P = cor@Wc2s ; S = sim@Ws2c
        mm128_kernel<<<1500, 128, 0, stream>>>(
            corO, Wc2s, P,
            simO, Ws2c, S, 750);
        // z2sim = c0*sim + c1*P + c2*(S@Wc2s) ; z2cor = c0*cor + c1*S + c2*(P@Ws2c)
        integ2_kernel<<<1500, 128, 0, stream>>>(
            S, Wc2s, simO, P, outSim,
            P, Ws2c, corO, S, outCor, 750, a1, a2, b2);
    } else {
        float* A = ws;
        float* B = A + 16000 * 256;
        float* C = B + 12000 * 256;
        float* simO = C + 6000 * 256;
        float* corO = simO + 6000 * 128;
        float* P    = corO + 6000 * 128;
        float* S    = P + 6000 * 128;

        for (int b = 0; b < 2; ++b) {
            const float* e0   = (b == 0) ? e0s : e0c;
            const float* e1   = (b == 0) ? e1s : e1c;
            const float* e2   = (b == 0) ? e2s : e2c;
            const float* Win  = (b == 0) ? Wins : Winc;
            const float* bin  = (b == 0) ? bins : binc;
            const float* Wout = (b == 0) ? Wouts : Woutc;
            const float* bout = (b == 0) ? bouts : boutc;
            const int* iD0 = (b == 0) ? idx_cor0 : idx_sim0;
            const int* iQ0 = (b == 0) ? idx_sim0 : idx_cor0;
            const int* iD1 = (b == 0) ? idx_cor1 : idx_sim1;
            const int* iQ1 = (b == 0) ? idx_sim1 : idx_cor1;
            float* branchOut = (b == 0) ? simO : corO;

            embed_fc_kernel<<<1000, 256, 0, stream>>>(x,
                e0, e1, e2, Win, bin, A,
                e0, e1, e2, Win, bin, A, 1000);
            coagg_kernel<10><<<12000, 256, 0, stream>>>(
                A, iD0, iQ0, B, A, iD0, iQ0, B, 12000, 1);
            coagg_kernel<5><<<6000, 256, 0, stream>>>(
                B, iD1, iQ1, C, B, iD1, iQ1, C, 6000, 0);
            fc_out_kernel<<<750, 128, 0, stream>>>(
                C, Wout, bout, branchOut,
                C, Wout, bout, branchOut, 750);
        }
        mm128_kernel<<<1500, 128, 0, stream>>>(
            corO, Wc2s, P,
            simO, Ws2c, S, 750);
        integ2_kernel<<<1500, 128, 0, stream>>>(
            S, Wc2s, simO, P, outSim,
            P, Ws2c, corO, S, outCor, 750, a1, a2, b2);
    }
}

// Round 5
// 225.899 us; speedup vs baseline: 4.6095x; 1.2488x over previous
//
#include <hip/hip_runtime.h>

#define CH 256

// DPP helper: v += dpp_move(v); bound_ctrl=true => out-of-range lanes read 0.
template <int CTRL>
__device__ __forceinline__ float dppAdd(float v) {
    const int m = __builtin_amdgcn_update_dpp(0, __builtin_bit_cast(int, v), CTRL, 0xf, 0xf, true);
    return v + __builtin_bit_cast(float, m);
}

// ---------------- embed + fc_input (dual-branch): 16 rows/block
__global__ __launch_bounds__(256) void embed_fc_kernel(
    const int* __restrict__ x,
    const float* __restrict__ e0a, const float* __restrict__ e1a, const float* __restrict__ e2a,
    const float* __restrict__ Wina, const float* __restrict__ bina, float* __restrict__ h0a,
    const float* __restrict__ e0b, const float* __restrict__ e1b, const float* __restrict__ e2b,
    const float* __restrict__ Winb, const float* __restrict__ binb, float* __restrict__ h0b,
    const int blocksPer)
{
    __shared__ float sE[16][128];
    int bid = blockIdx.x;
    const float *e0, *e1, *e2, *Win, *bin;
    float* h0;
    if (bid < blocksPer) { e0 = e0a; e1 = e1a; e2 = e2a; Win = Wina; bin = bina; h0 = h0a; }
    else { bid -= blocksPer; e0 = e0b; e1 = e1b; e2 = e2b; Win = Winb; bin = binb; h0 = h0b; }

    const int row0 = bid * 16;
    const int t = threadIdx.x;
    for (int i = t; i < 16 * 128; i += 256) {
        const int r = i >> 7, k = i & 127;
        const int row = row0 + r;
        float v;
        if (k < 64)      v = e0[x[row * 3 + 0] * 64 + k];
        else if (k < 96) v = e1[x[row * 3 + 1] * 32 + (k - 64)];
        else             v = e2[x[row * 3 + 2] * 32 + (k - 96)];
        sE[r][k] = v;
    }
    __syncthreads();
    const int j = t;
    float acc[16];
    const float b = bin[j];
#pragma unroll
    for (int r = 0; r < 16; ++r) acc[r] = b;
    for (int k = 0; k < 128; ++k) {
        const float wv = Win[k * 256 + j];
#pragma unroll
        for (int r = 0; r < 16; ++r) acc[r] += sE[r][k] * wv;
    }
#pragma unroll
    for (int r = 0; r < 16; ++r) h0[(size_t)(row0 + r) * 256 + j] = acc[r];
}

// ---------------- co-attention aggregation (dual-branch); one block per dst node
// L[k][m]=<D[k],Q[m]>; AC=row-softmax; AS[c][m]=softmax_m L[m][c]
// sum_k h[k] = [ sum Q | sum_m w_m D_m | sum_j u_j Q_j ], w=colsum(AS), u=AC^T w
template <int K>
__global__ __launch_bounds__(256) void coagg_kernel(
    const float* __restrict__ fa, const int* __restrict__ iDa, const int* __restrict__ iQa,
    float* __restrict__ oa,
    const float* __restrict__ fb, const int* __restrict__ iDb, const int* __restrict__ iQb,
    float* __restrict__ ob,
    const int nPer, const int relu)
{
    __shared__ __align__(16) float sD[K][256];
    __shared__ __align__(16) float sQ[K][256];
    __shared__ float sL[K][K];
    __shared__ float sAC[K][K];
    __shared__ float sAS[K][K];
    __shared__ float sw_[K], su_[K];
    __shared__ __align__(16) float sHsum[768];

    int n = blockIdx.x;
    const float* feat; const int* idxD; const int* idxQ; float* outp;
    if (n < nPer) { feat = fa; idxD = iDa; idxQ = iQa; outp = oa; }
    else { n -= nPer; feat = fb; idxD = iDb; idxQ = iQb; outp = ob; }

    const int t = threadIdx.x;
    const int w = t >> 6, lane = t & 63;

    // gather D,Q rows into LDS (coalesced b128 per row)
    {
        const float4* fp = (const float4*)feat;
        for (int i = t; i < K * 64; i += 256) {
            const int row = i >> 6, c = i & 63;
            ((float4*)&sD[row][0])[c] = fp[(size_t)idxD[n * K + row] * 64 + c];
            ((float4*)&sQ[row][0])[c] = fp[(size_t)idxQ[n * K + row] * 64 + c];
        }
    }
    const float resid = feat[(size_t)n * CH + t];   // prefetch residual (used at the end)
    __syncthreads();

    // all Q rows into registers (per wave; lane holds float4 slice; static indices only)
    float4 Q[K];
#pragma unroll
    for (int m = 0; m < K; ++m) Q[m] = ((const float4*)&sQ[m][0])[lane];

    // L-phase: wave w owns rows k = w + 4*kk.
    // 2-pair reduction, all on the VALU pipe:
    //   v_permlane32_swap_b32(s0, s1): s0.hi <-> s1.lo. Then r = s0+s1 puts
    //   pair-m0 2-fold partials in lanes 0-31 and pair-(m0+1) in lanes 32-63.
    //   DPP ladder row_shr:1/2/4/8 + row_bcast:15 -> lane31 = dot(m0),
    //   lane63 = dot(m0+1) (bcast reads old values; halves stay independent).
#pragma unroll
    for (int kk = 0; kk < (K + 3) / 4; ++kk) {
        const int k = w + kk * 4;
        if (k < K) {                          // wave-uniform branch
            const float4 d = ((const float4*)&sD[k][0])[lane];
#pragma unroll
            for (int m0 = 0; m0 < K; m0 += 2) {
                const float4 q0 = Q[m0];
                float s0 = d.x * q0.x + d.y * q0.y + d.z * q0.z + d.w * q0.w;
                float s1 = 0.f;
                if (m0 + 1 < K) {             // compile-time after unroll
                    const float4 q1 = Q[m0 + 1];
                    s1 = d.x * q1.x + d.y * q1.y + d.z * q1.z + d.w * q1.w;
                }
                asm volatile("v_permlane32_swap_b32 %0, %1" : "+v"(s0), "+v"(s1));
                float r = s0 + s1;
                r = dppAdd<0x111>(r);   // row_shr:1
                r = dppAdd<0x112>(r);   // row_shr:2
                r = dppAdd<0x114>(r);   // row_shr:4
                r = dppAdd<0x118>(r);   // row_shr:8
                r = dppAdd<0x142>(r);   // row_bcast:15
                if (lane == 31) sL[k][m0] = r;
                if (lane == 63 && m0 + 1 < K) sL[k][m0 + 1] = r;
            }
        }
    }
    __syncthreads();

    // stage A: softmaxes (wave 0; two disjoint lane groups; read sL only)
    if (w == 0) {
        if (lane < K) {                       // AC row = lane
            float e_[K], mx = -1e30f;
#pragma unroll
            for (int m = 0; m < K; ++m) mx = fmaxf(mx, sL[lane][m]);
            float ssum = 0.f;
#pragma unroll
            for (int m = 0; m < K; ++m) { e_[m] = __expf(sL[lane][m] - mx); ssum += e_[m]; }
            const float inv = 1.f / ssum;
#pragma unroll
            for (int m = 0; m < K; ++m) sAC[lane][m] = e_[m] * inv;
        }
        const int c = lane - 16;
        if (c >= 0 && c < K) {                // AS row c = softmax of column c of L
            float e_[K], mx = -1e30f;
#pragma unroll
            for (int m = 0; m < K; ++m) mx = fmaxf(mx, sL[m][c]);
            float ssum = 0.f;
#pragma unroll
            for (int m = 0; m < K; ++m) { e_[m] = __expf(sL[m][c] - mx); ssum += e_[m]; }
            const float inv = 1.f / ssum;
#pragma unroll
            for (int m = 0; m < K; ++m) sAS[c][m] = e_[m] * inv;
        }
    }
    __syncthreads();

    // stage B: w[m] = colsum(AS)
    if (t < K) {
        float s = 0.f;
#pragma unroll
        for (int k2 = 0; k2 < K; ++k2) s += sAS[k2][t];
        sw_[t] = s;
    }
    __syncthreads();

    // stage C: u[j] = sum_m w[m]*AC[m][j]
    if (t < K) {
        float s = 0.f;
#pragma unroll
        for (int m = 0; m < K; ++m) s += sw_[m] * sAC[m][t];
        su_[t] = s;
    }
    __syncthreads();

    // stage D: weighted row sums (wave 0; lane owns float4 feature slice)
    if (w == 0) {
        float4 h0v = make_float4(0.f, 0.f, 0.f, 0.f);
        float4 h1v = make_float4(0.f, 0.f, 0.f, 0.f);
        float4 h2v = make_float4(0.f, 0.f, 0.f, 0.f);
#pragma unroll
        for (int kx = 0; kx < K; ++kx) {
            const float wk = sw_[kx], uk = su_[kx];
            const float4 q = Q[kx];
            const float4 d = ((const float4*)&sD[kx][0])[lane];
            h0v.x += q.x;      h0v.y += q.y;      h0v.z += q.z;      h0v.w += q.w;
            h1v.x += wk * d.x; h1v.y += wk * d.y; h1v.z += wk * d.z; h1v.w += wk * d.w;
            h2v.x += uk * q.x; h2v.y += uk * q.y; h2v.z += uk * q.z; h2v.w += uk * q.w;
        }
        ((float4*)&sHsum[0])[lane]   = h0v;
        ((float4*)&sHsum[256])[lane] = h1v;
        ((float4*)&sHsum[512])[lane] = h2v;
    }
    __syncthreads();

    // stage E: pool3 + mean_k + residual
    const float acc = sHsum[3 * t] + sHsum[3 * t + 1] + sHsum[3 * t + 2];
    float v = resid + acc * (1.0f / (3.0f * K));
    if (relu) v = fmaxf(v, 0.f);
    outp[(size_t)n * CH + t] = v;
}

// ---------------- h2[.x256] @ Wout[256x128] + bout (dual-branch)
__global__ __launch_bounds__(128) void fc_out_kernel(
    const float* __restrict__ h2a, const float* __restrict__ Wouta,
    const float* __restrict__ bouta, float* __restrict__ oa,
    const float* __restrict__ h2b, const float* __restrict__ Woutb,
    const float* __restrict__ boutb, float* __restrict__ ob,
    const int blocksPer)
{
    __shared__ float sIn[8][256];
    int bid = blockIdx.x;
    const float *h2, *Wout, *bout; float* outp;
    if (bid < blocksPer) { h2 = h2a; Wout = Wouta; bout = bouta; outp = oa; }
    else { bid -= blocksPer; h2 = h2b; Wout = Woutb; bout = boutb; outp = ob; }

    const int row0 = bid * 8;
    const int t = threadIdx.x;
    for (int i = t; i < 8 * 256; i += 128) sIn[i >> 8][i & 255] = h2[(size_t)row0 * 256 + i];
    __syncthreads();
    float acc[8];
    const float b = bout[t];
#pragma unroll
    for (int r = 0; r < 8; ++r) acc[r] = b;
    for (int k = 0; k < 256; ++k) {
        const float wv = Wout[k * 128 + t];
#pragma unroll
        for (int r = 0; r < 8; ++r) acc[r] += sIn[r][k] * wv;
    }
#pragma unroll
    for (int r = 0; r < 8; ++r) outp[(size_t)(row0 + r) * 128 + t] = acc[r];
}

// ---------------- out = in[.x128] @ W[128x128] (dual)
__global__ __launch_bounds__(128) void mm128_kernel(
    const float* __restrict__ ina, const float* __restrict__ Wa, float* __restrict__ oa,
    const float* __restrict__ inb, const float* __restrict__ Wb, float* __restrict__ ob,
    const int blocksPer)
{
    __shared__ float sIn[8][128];
    int bid = blockIdx.x;
    const float *inp, *W; float* outp;
    if (bid < blocksPer) { inp = ina; W = Wa; outp = oa; }
    else { bid -= blocksPer; inp = inb; W = Wb; outp = ob; }

    const int row0 = bid * 8;
    const int t = threadIdx.x;
    for (int i = t; i < 8 * 128; i += 128) sIn[i >> 7][i & 127] = inp[(size_t)row0 * 128 + i];
    __syncthreads();
    float acc[8];
#pragma unroll
    for (int r = 0; r < 8; ++r) acc[r] = 0.f;
    for (int k = 0; k < 128; ++k) {
        const float wv = W[k * 128 + t];
#pragma unroll
        for (int r = 0; r < 8; ++r) acc[r] += sIn[r][k] * wv;
    }
#pragma unroll
    for (int r = 0; r < 8; ++r) outp[(size_t)(row0 + r) * 128 + t] = acc[r];
}

// ---------------- z2 = c0*base1 + c1*base2 + c2*(mm_in @ W)   (dual)
__global__ __launch_bounds__(128) void integ2_kernel(
    const float* __restrict__ mma, const float* __restrict__ Wa,
    const float* __restrict__ b1a, const float* __restrict__ b2a, float* __restrict__ oa,
    const float* __restrict__ mmb, const float* __restrict__ Wb,
    const float* __restrict__ b1b, const float* __restrict__ b2b, float* __restrict__ ob,
    const int blocksPer,
    const float* __restrict__ a1p, const float* __restrict__ a2p, const float* __restrict__ b2p)
{
    const float a1 = *a1p, a2 = *a2p, b2 = *b2p;
    const float c0 = 1.f - a2 - b2;
    const float c1 = a2 + b2 * (1.f - a1);
    const float c2 = b2 * a1;

    __shared__ float sIn[8][128];
    int bid = blockIdx.x;
    const float *mm_in, *W, *base1, *base2; float* outp;
    if (bid < blocksPer) { mm_in = mma; W = Wa; base1 = b1a; base2 = b2a; outp = oa; }
    else { bid -= blocksPer; mm_in = mmb; W = Wb; base1 = b1b; base2 = b2b; outp = ob; }

    const int row0 = bid * 8;
    const int t = threadIdx.x;
    for (int i = t; i < 8 * 128; i += 128) sIn[i >> 7][i & 127] = mm_in[(size_t)row0 * 128 + i];
    __syncthreads();
    float acc[8];
#pragma unroll
    for (int r = 0; r < 8; ++r) acc[r] = 0.f;
    for (int k = 0; k < 128; ++k) {
        const float wv = W[k * 128 + t];
#pragma unroll
        for (int r = 0; r < 8; ++r) acc[r] += sIn[r][k] * wv;
    }
#pragma unroll
    for (int r = 0; r < 8; ++r) {
        const size_t idx = (size_t)(row0 + r) * 128 + t;
        outp[idx] = c0 * base1[idx] + c1 * base2[idx] + c2 * acc[r];
    }
}

extern "C" void kernel_launch(void* const* d_in, const int* in_sizes, int n_in,
                              void* d_out, int out_size, void* d_ws, size_t ws_size,
                              hipStream_t stream)
{
    const int* x        = (const int*)d_in[0];
    const int* idx_sim0 = (const int*)d_in[1];
    const int* idx_cor0 = (const int*)d_in[2];
    const int* idx_sim1 = (const int*)d_in[3];
    const int* idx_cor1 = (const int*)d_in[4];
    const float* e0s  = (const float*)d_in[5];
    const float* e1s  = (const float*)d_in[6];
    const float* e2s  = (const float*)d_in[7];
    const float* Wins = (const float*)d_in[8];
    const float* bins = (const float*)d_in[9];
    const float* Wouts= (const float*)d_in[10];
    const float* bouts= (const float*)d_in[11];
    const float* e0c  = (const float*)d_in[12];
    const float* e1c  = (const float*)d_in[13];
    const float* e2c  = (const float*)d_in[14];
    const float* Winc = (const float*)d_in[15];
    const float* binc = (const float*)d_in[16];
    const float* Woutc= (const float*)d_in[17];
    const float* boutc= (const float*)d_in[18];
    const float* Ws2c = (const float*)d_in[19];
    const float* Wc2s = (const float*)d_in[20];
    const float* a1 = (const float*)d_in[21];
    const float* a2 = (const float*)d_in[22];
    const float* b2 = (const float*)d_in[23];

    float* outSim = (float*)d_out;
    float* outCor = outSim + 6000 * 128;

    float* ws = (float*)d_ws;
    const size_t needMerged = (size_t)(2 * 16000 * 256 + 2 * 12000 * 256 + 2 * 6000 * 256 + 4 * 6000 * 128) * 4;
    const bool merged = ws_size >= needMerged;

    if (merged) {
        float* A0 = ws;
        float* A1 = A0 + 16000 * 256;
        float* B0 = A1 + 16000 * 256;
        float* B1 = B0 + 12000 * 256;
        float* C0 = B1 + 12000 * 256;
        float* C1 = C0 + 6000 * 256;
        float* simO = C1 + 6000 * 256;
        float* corO = simO + 6000 * 128;
        float* P    = corO + 6000 * 128;
        float* S    = P + 6000 * 128;

        embed_fc_kernel<<<2000, 256, 0, stream>>>(x,
            e0s, e1s, e2s, Wins, bins, A0,
            e0c, e1c, e2c, Winc, binc, A1, 1000);
        // sim: D=feat[idx_cor], Q=feat[idx_sim]; cor: swapped
        coagg_kernel<10><<<24000, 256, 0, stream>>>(
            A0, idx_cor0, idx_sim0, B0,
            A1, idx_sim0, idx_cor0, B1, 12000, 1);
        coagg_kernel<5><<<12000, 256, 0, stream>>>(
            B0, idx_cor1, idx_sim1, C0,
            B1, idx_sim1, idx_cor1, C1, 6000, 0);
        fc_out_kernel<<<1500, 128, 0, stream>>>(
            C0, Wouts, bouts, simO,
            C1, Woutc, boutc, corO, 750);
        // P = cor@Wc2s ; S = sim@Ws2c
        mm128_kernel<<<1500, 128, 0, stream>>>(
            corO, Wc2s, P,
            simO, Ws2c, S, 750);
        // z2sim = c0*sim + c1*P + c2*(S@Wc2s) ; z2cor = c0*cor + c1*S + c2*(P@Ws2c)
        integ2_kernel<<<1500, 128, 0, stream>>>(
            S, Wc2s, simO, P, outSim,
            P, Ws2c, corO, S, outCor, 750, a1, a2, b2);
    } else {
        float* A = ws;
        float* B = A + 16000 * 256;
        float* C = B + 12000 * 256;
        float* simO = C + 6000 * 256;
        float* corO = simO + 6000 * 128;
        float* P    = corO + 6000 * 128;
        float* S    = P + 6000 * 128;

        for (int b = 0; b < 2; ++b) {
            const float* e0   = (b == 0) ? e0s : e0c;
            const float* e1   = (b == 0) ? e1s : e1c;
            const float* e2   = (b == 0) ? e2s : e2c;
            const float* Win  = (b == 0) ? Wins : Winc;
            const float* bin  = (b == 0) ? bins : binc;
            const float* Wout = (b == 0) ? Wouts : Woutc;
            const float* bout = (b == 0) ? bouts : boutc;
            const int* iD0 = (b == 0) ? idx_cor0 : idx_sim0;
            const int* iQ0 = (b == 0) ? idx_sim0 : idx_cor0;
            const int* iD1 = (b == 0) ? idx_cor1 : idx_sim1;
            const int* iQ1 = (b == 0) ? idx_sim1 : idx_cor1;
            float* branchOut = (b == 0) ? simO : corO;

            embed_fc_kernel<<<1000, 256, 0, stream>>>(x,
                e0, e1, e2, Win, bin, A,
                e0, e1, e2, Win, bin, A, 1000);
            coagg_kernel<10><<<12000, 256, 0, stream>>>(
                A, iD0, iQ0, B, A, iD0, iQ0, B, 12000, 1);
            coagg_kernel<5><<<6000, 256, 0, stream>>>(
                B, iD1, iQ1, C, B, iD1, iQ1, C, 6000, 0);
            fc_out_kernel<<<750, 128, 0, stream>>>(
                C, Wout, bout, branchOut,
                C, Wout, bout, branchOut, 750);
        }
        mm128_kernel<<<1500, 128, 0, stream>>>(
            corO, Wc2s, P,
            simO, Ws2c, S, 750);
        integ2_kernel<<<1500, 128, 0, stream>>>(
            S, Wc2s, simO, P, outSim,
            P, Ws2c, corO, S, outCor, 750, a1, a2, b2);
    }
}

// Round 6
// 204.347 us; speedup vs baseline: 5.0956x; 1.1055x over previous
//
#include <hip/hip_runtime.h>

#define CH 256

// DPP helper: v += dpp_move(v); bound_ctrl=true => out-of-range lanes read 0.
template <int CTRL>
__device__ __forceinline__ float dppAdd(float v) {
    const int m = __builtin_amdgcn_update_dpp(0, __builtin_bit_cast(int, v), CTRL, 0xf, 0xf, true);
    return v + __builtin_bit_cast(float, m);
}

// ---------------- embed + fc_input (dual-branch): 16 rows/block
__global__ __launch_bounds__(256) void embed_fc_kernel(
    const int* __restrict__ x,
    const float* __restrict__ e0a, const float* __restrict__ e1a, const float* __restrict__ e2a,
    const float* __restrict__ Wina, const float* __restrict__ bina, float* __restrict__ h0a,
    const float* __restrict__ e0b, const float* __restrict__ e1b, const float* __restrict__ e2b,
    const float* __restrict__ Winb, const float* __restrict__ binb, float* __restrict__ h0b,
    const int blocksPer)
{
    __shared__ float sE[16][128];
    int bid = blockIdx.x;
    const float *e0, *e1, *e2, *Win, *bin;
    float* h0;
    if (bid < blocksPer) { e0 = e0a; e1 = e1a; e2 = e2a; Win = Wina; bin = bina; h0 = h0a; }
    else { bid -= blocksPer; e0 = e0b; e1 = e1b; e2 = e2b; Win = Winb; bin = binb; h0 = h0b; }

    const int row0 = bid * 16;
    const int t = threadIdx.x;
    for (int i = t; i < 16 * 128; i += 256) {
        const int r = i >> 7, k = i & 127;
        const int row = row0 + r;
        float v;
        if (k < 64)      v = e0[x[row * 3 + 0] * 64 + k];
        else if (k < 96) v = e1[x[row * 3 + 1] * 32 + (k - 64)];
        else             v = e2[x[row * 3 + 2] * 32 + (k - 96)];
        sE[r][k] = v;
    }
    __syncthreads();
    const int j = t;
    float acc[16];
    const float b = bin[j];
#pragma unroll
    for (int r = 0; r < 16; ++r) acc[r] = b;
    for (int k = 0; k < 128; ++k) {
        const float wv = Win[k * 256 + j];
#pragma unroll
        for (int r = 0; r < 16; ++r) acc[r] += sE[r][k] * wv;
    }
#pragma unroll
    for (int r = 0; r < 16; ++r) h0[(size_t)(row0 + r) * 256 + j] = acc[r];
}

// ---------------- co-attention aggregation (dual-branch); ONE WAVE per dst node
// L[k][m]=<D[k],Q[m]>; AC=row-softmax; AS[c][m]=softmax_m L[m][c]
// sum_k h[k] = [ sum Q | sum_m w_m D_m | sum_j u_j Q_j ], w=colsum(AS), u=AC^T w
// 4 waves/block, no __syncthreads: per-wave LDS slices, intra-wave RAW ordered
// by program order + compiler lgkmcnt. D,Q live in registers (float4/lane).
template <int K>
__global__ __launch_bounds__(256, 4) void coagg_kernel(
    const float* __restrict__ fa, const int* __restrict__ iDa, const int* __restrict__ iQa,
    float* __restrict__ oa,
    const float* __restrict__ fb, const int* __restrict__ iDb, const int* __restrict__ iQb,
    float* __restrict__ ob,
    const int nPer, const int relu)
{
    __shared__ float sL[4][K][K];
    __shared__ float sAC[4][K][K];
    __shared__ float sAS[4][K][K];
    __shared__ float sw_[4][K], su_[4][K];
    __shared__ __align__(16) float sHsum[4][768];

    const int t = threadIdx.x;
    const int wv = t >> 6, lane = t & 63;
    int n = blockIdx.x * 4 + wv;             // grid sized so 4 | total nodes

    const float* feat; const int* idxD; const int* idxQ; float* outp;
    if (n < nPer) { feat = fa; idxD = iDa; idxQ = iQa; outp = oa; }
    else { n -= nPer; feat = fb; idxD = iDb; idxQ = iQb; outp = ob; }

    const float4* fp = (const float4*)feat;

    // gather D,Q rows into registers (lane owns float4 feature slice)
    float4 d[K], q[K];
#pragma unroll
    for (int k = 0; k < K; ++k) {
        const int rD = idxD[n * K + k];
        const int rQ = idxQ[n * K + k];
        d[k] = fp[(size_t)rD * 64 + lane];
        q[k] = fp[(size_t)rQ * 64 + lane];
    }
    const float4 resid = fp[(size_t)n * 64 + lane];

    // L-phase: verified 2-pair permlane32_swap + DPP ladder (round 5).
    //   lane31 -> dot(m0), lane63 -> dot(m0+1)
#pragma unroll
    for (int k = 0; k < K; ++k) {
        const float4 dd = d[k];
#pragma unroll
        for (int m0 = 0; m0 < K; m0 += 2) {
            const float4 q0 = q[m0];
            float s0 = dd.x * q0.x + dd.y * q0.y + dd.z * q0.z + dd.w * q0.w;
            float s1 = 0.f;
            if (m0 + 1 < K) {                 // compile-time after unroll
                const float4 q1 = q[m0 + 1];
                s1 = dd.x * q1.x + dd.y * q1.y + dd.z * q1.z + dd.w * q1.w;
            }
            asm volatile("v_permlane32_swap_b32 %0, %1" : "+v"(s0), "+v"(s1));
            float r = s0 + s1;
            r = dppAdd<0x111>(r);   // row_shr:1
            r = dppAdd<0x112>(r);   // row_shr:2
            r = dppAdd<0x114>(r);   // row_shr:4
            r = dppAdd<0x118>(r);   // row_shr:8
            r = dppAdd<0x142>(r);   // row_bcast:15
            if (lane == 31) sL[wv][k][m0] = r;
            if (lane == 63 && m0 + 1 < K) sL[wv][k][m0 + 1] = r;
        }
    }

    // stage A: softmaxes (lanes 0..K-1: AC rows; lanes 16..16+K-1: AS cols)
    if (lane < K) {
        float e_[K], mx = -1e30f;
#pragma unroll
        for (int m = 0; m < K; ++m) mx = fmaxf(mx, sL[wv][lane][m]);
        float ssum = 0.f;
#pragma unroll
        for (int m = 0; m < K; ++m) { e_[m] = __expf(sL[wv][lane][m] - mx); ssum += e_[m]; }
        const float inv = 1.f / ssum;
#pragma unroll
        for (int m = 0; m < K; ++m) sAC[wv][lane][m] = e_[m] * inv;
    }
    {
        const int c = lane - 16;
        if (c >= 0 && c < K) {
            float e_[K], mx = -1e30f;
#pragma unroll
            for (int m = 0; m < K; ++m) mx = fmaxf(mx, sL[wv][m][c]);
            float ssum = 0.f;
#pragma unroll
            for (int m = 0; m < K; ++m) { e_[m] = __expf(sL[wv][m][c] - mx); ssum += e_[m]; }
            const float inv = 1.f / ssum;
#pragma unroll
            for (int m = 0; m < K; ++m) sAS[wv][c][m] = e_[m] * inv;
        }
    }
    // stage B: w[m] = colsum(AS)   (lanes 32..32+K-1; reads stage-A writes)
    {
        const int m2 = lane - 32;
        if (m2 >= 0 && m2 < K) {
            float s = 0.f;
#pragma unroll
            for (int k2 = 0; k2 < K; ++k2) s += sAS[wv][k2][m2];
            sw_[wv][m2] = s;
        }
    }
    // stage C: u[j] = sum_m w[m]*AC[m][j]   (lanes 48..48+K-1)
    {
        const int j2 = lane - 48;
        if (j2 >= 0 && j2 < K) {
            float s = 0.f;
#pragma unroll
            for (int m = 0; m < K; ++m) s += sw_[wv][m] * sAC[wv][m][j2];
            su_[wv][j2] = s;
        }
    }

    // stage D: weighted row sums (all lanes; D,Q in regs; w,u broadcast reads)
    float4 h0v = make_float4(0.f, 0.f, 0.f, 0.f);
    float4 h1v = make_float4(0.f, 0.f, 0.f, 0.f);
    float4 h2v = make_float4(0.f, 0.f, 0.f, 0.f);
#pragma unroll
    for (int kx = 0; kx < K; ++kx) {
        const float wk = sw_[wv][kx];
        const float uk = su_[wv][kx];
        const float4 qq = q[kx];
        const float4 dd = d[kx];
        h0v.x += qq.x;      h0v.y += qq.y;      h0v.z += qq.z;      h0v.w += qq.w;
        h1v.x += wk * dd.x; h1v.y += wk * dd.y; h1v.z += wk * dd.z; h1v.w += wk * dd.w;
        h2v.x += uk * qq.x; h2v.y += uk * qq.y; h2v.z += uk * qq.z; h2v.w += uk * qq.w;
    }
    ((float4*)&sHsum[wv][0])[lane]       = h0v;
    ((float4*)&sHsum[wv][0])[64 + lane]  = h1v;
    ((float4*)&sHsum[wv][0])[128 + lane] = h2v;

    // stage E: pool3 + mean_k + residual (reads same-wave sHsum)
    float ov[4];
#pragma unroll
    for (int i = 0; i < 4; ++i) {
        const int f = lane * 4 + i;
        ov[i] = (sHsum[wv][3 * f] + sHsum[wv][3 * f + 1] + sHsum[wv][3 * f + 2])
                * (1.0f / (3.0f * K));
    }
    float4 o = make_float4(resid.x + ov[0], resid.y + ov[1],
                           resid.z + ov[2], resid.w + ov[3]);
    if (relu) {
        o.x = fmaxf(o.x, 0.f); o.y = fmaxf(o.y, 0.f);
        o.z = fmaxf(o.z, 0.f); o.w = fmaxf(o.w, 0.f);
    }
    ((float4*)outp)[(size_t)n * 64 + lane] = o;
}

// ---------------- h2[.x256] @ Wout[256x128] + bout (dual-branch)
__global__ __launch_bounds__(128) void fc_out_kernel(
    const float* __restrict__ h2a, const float* __restrict__ Wouta,
    const float* __restrict__ bouta, float* __restrict__ oa,
    const float* __restrict__ h2b, const float* __restrict__ Woutb,
    const float* __restrict__ boutb, float* __restrict__ ob,
    const int blocksPer)
{
    __shared__ float sIn[8][256];
    int bid = blockIdx.x;
    const float *h2, *Wout, *bout; float* outp;
    if (bid < blocksPer) { h2 = h2a; Wout = Wouta; bout = bouta; outp = oa; }
    else { bid -= blocksPer; h2 = h2b; Wout = Woutb; bout = boutb; outp = ob; }

    const int row0 = bid * 8;
    const int t = threadIdx.x;
    for (int i = t; i < 8 * 256; i += 128) sIn[i >> 8][i & 255] = h2[(size_t)row0 * 256 + i];
    __syncthreads();
    float acc[8];
    const float b = bout[t];
#pragma unroll
    for (int r = 0; r < 8; ++r) acc[r] = b;
    for (int k = 0; k < 256; ++k) {
        const float wv = Wout[k * 128 + t];
#pragma unroll
        for (int r = 0; r < 8; ++r) acc[r] += sIn[r][k] * wv;
    }
#pragma unroll
    for (int r = 0; r < 8; ++r) outp[(size_t)(row0 + r) * 128 + t] = acc[r];
}

// ---------------- out = in[.x128] @ W[128x128] (dual)
__global__ __launch_bounds__(128) void mm128_kernel(
    const float* __restrict__ ina, const float* __restrict__ Wa, float* __restrict__ oa,
    const float* __restrict__ inb, const float* __restrict__ Wb, float* __restrict__ ob,
    const int blocksPer)
{
    __shared__ float sIn[8][128];
    int bid = blockIdx.x;
    const float *inp, *W; float* outp;
    if (bid < blocksPer) { inp = ina; W = Wa; outp = oa; }
    else { bid -= blocksPer; inp = inb; W = Wb; outp = ob; }

    const int row0 = bid * 8;
    const int t = threadIdx.x;
    for (int i = t; i < 8 * 128; i += 128) sIn[i >> 7][i & 127] = inp[(size_t)row0 * 128 + i];
    __syncthreads();
    float acc[8];
#pragma unroll
    for (int r = 0; r < 8; ++r) acc[r] = 0.f;
    for (int k = 0; k < 128; ++k) {
        const float wv = W[k * 128 + t];
#pragma unroll
        for (int r = 0; r < 8; ++r) acc[r] += sIn[r][k] * wv;
    }
#pragma unroll
    for (int r = 0; r < 8; ++r) outp[(size_t)(row0 + r) * 128 + t] = acc[r];
}

// ---------------- z2 = c0*base1 + c1*base2 + c2*(mm_in @ W)   (dual)
__global__ __launch_bounds__(128) void integ2_kernel(
    const float* __restrict__ mma, const float* __restrict__ Wa,
    const float* __restrict__ b1a, const float* __restrict__ b2a, float* __restrict__ oa,
    const float* __restrict__ mmb, const float* __restrict__ Wb,
    const float* __restrict__ b1b, const float* __restrict__ b2b, float* __restrict__ ob,
    const int blocksPer,
    const float* __restrict__ a1p, const float* __restrict__ a2p, const float* __restrict__ b2p)
{
    const float a1 = *a1p, a2 = *a2p, b2 = *b2p;
    const float c0 = 1.f - a2 - b2;
    const float c1 = a2 + b2 * (1.f - a1);
    const float c2 = b2 * a1;

    __shared__ float sIn[8][128];
    int bid = blockIdx.x;
    const float *mm_in, *W, *base1, *base2; float* outp;
    if (bid < blocksPer) { mm_in = mma; W = Wa; base1 = b1a; base2 = b2a; outp = oa; }
    else { bid -= blocksPer; mm_in = mmb; W = Wb; base1 = b1b; base2 = b2b; outp = ob; }

    const int row0 = bid * 8;
    const int t = threadIdx.x;
    for (int i = t; i < 8 * 128; i += 128) sIn[i >> 7][i & 127] = mm_in[(size_t)row0 * 128 + i];
    __syncthreads();
    float acc[8];
#pragma unroll
    for (int r = 0; r < 8; ++r) acc[r] = 0.f;
    for (int k = 0; k < 128; ++k) {
        const float wv = W[k * 128 + t];
#pragma unroll
        for (int r = 0; r < 8; ++r) acc[r] += sIn[r][k] * wv;
    }
#pragma unroll
    for (int r = 0; r < 8; ++r) {
        const size_t idx = (size_t)(row0 + r) * 128 + t;
        outp[idx] = c0 * base1[idx] + c1 * base2[idx] + c2 * acc[r];
    }
}

extern "C" void kernel_launch(void* const* d_in, const int* in_sizes, int n_in,
                              void* d_out, int out_size, void* d_ws, size_t ws_size,
                              hipStream_t stream)
{
    const int* x        = (const int*)d_in[0];
    const int* idx_sim0 = (const int*)d_in[1];
    const int* idx_cor0 = (const int*)d_in[2];
    const int* idx_sim1 = (const int*)d_in[3];
    const int* idx_cor1 = (const int*)d_in[4];
    const float* e0s  = (const float*)d_in[5];
    const float* e1s  = (const float*)d_in[6];
    const float* e2s  = (const float*)d_in[7];
    const float* Wins = (const float*)d_in[8];
    const float* bins = (const float*)d_in[9];
    const float* Wouts= (const float*)d_in[10];
    const float* bouts= (const float*)d_in[11];
    const float* e0c  = (const float*)d_in[12];
    const float* e1c  = (const float*)d_in[13];
    const float* e2c  = (const float*)d_in[14];
    const float* Winc = (const float*)d_in[15];
    const float* binc = (const float*)d_in[16];
    const float* Woutc= (const float*)d_in[17];
    const float* boutc= (const float*)d_in[18];
    const float* Ws2c = (const float*)d_in[19];
    const float* Wc2s = (const float*)d_in[20];
    const float* a1 = (const float*)d_in[21];
    const float* a2 = (const float*)d_in[22];
    const float* b2 = (const float*)d_in[23];

    float* outSim = (float*)d_out;
    float* outCor = outSim + 6000 * 128;

    float* ws = (float*)d_ws;
    const size_t needMerged = (size_t)(2 * 16000 * 256 + 2 * 12000 * 256 + 2 * 6000 * 256 + 4 * 6000 * 128) * 4;
    const bool merged = ws_size >= needMerged;

    if (merged) {
        float* A0 = ws;
        float* A1 = A0 + 16000 * 256;
        float* B0 = A1 + 16000 * 256;
        float* B1 = B0 + 12000 * 256;
        float* C0 = B1 + 12000 * 256;
        float* C1 = C0 + 6000 * 256;
        float* simO = C1 + 6000 * 256;
        float* corO = simO + 6000 * 128;
        float* P    = corO + 6000 * 128;
        float* S    = P + 6000 * 128;

        embed_fc_kernel<<<2000, 256, 0, stream>>>(x,
            e0s, e1s, e2s, Wins, bins, A0,
            e0c, e1c, e2c, Winc, binc, A1, 1000);
        // sim: D=feat[idx_cor], Q=feat[idx_sim]; cor: swapped
        coagg_kernel<10><<<6000, 256, 0, stream>>>(
            A0, idx_cor0, idx_sim0, B0,
            A1, idx_sim0, idx_cor0, B1, 12000, 1);
        coagg_kernel<5><<<3000, 256, 0, stream>>>(
            B0, idx_cor1, idx_sim1, C0,
            B1, idx_sim1, idx_cor1, C1, 6000, 0);
        fc_out_kernel<<<1500, 128, 0, stream>>>(
            C0, Wouts, bouts, simO,
            C1, Woutc, boutc, corO, 750);
        // P = cor@Wc2s ; S = sim@Ws2c
        mm128_kernel<<<1500, 128, 0, stream>>>(
            corO, Wc2s, P,
            simO, Ws2c, S, 750);
        // z2sim = c0*sim + c1*P + c2*(S@Wc2s) ; z2cor = c0*cor + c1*S + c2*(P@Ws2c)
        integ2_kernel<<<1500, 128, 0, stream>>>(
            S, Wc2s, simO, P, outSim,
            P, Ws2c, corO, S, outCor, 750, a1, a2, b2);
    } else {
        float* A = ws;
        float* B = A + 16000 * 256;
        float* C = B + 12000 * 256;
        float* simO = C + 6000 * 256;
        float* corO = simO + 6000 * 128;
        float* P    = corO + 6000 * 128;
        float* S    = P + 6000 * 128;

        for (int b = 0; b < 2; ++b) {
            const float* e0   = (b == 0) ? e0s : e0c;
            const float* e1   = (b == 0) ? e1s : e1c;
            const float* e2   = (b == 0) ? e2s : e2c;
            const float* Win  = (b == 0) ? Wins : Winc;
            const float* bin  = (b == 0) ? bins : binc;
            const float* Wout = (b == 0) ? Wouts : Woutc;
            const float* bout = (b == 0) ? bouts : boutc;
            const int* iD0 = (b == 0) ? idx_cor0 : idx_sim0;
            const int* iQ0 = (b == 0) ? idx_sim0 : idx_cor0;
            const int* iD1 = (b == 0) ? idx_cor1 : idx_sim1;
            const int* iQ1 = (b == 0) ? idx_sim1 : idx_cor1;
            float* branchOut = (b == 0) ? simO : corO;

            embed_fc_kernel<<<1000, 256, 0, stream>>>(x,
                e0, e1, e2, Win, bin, A,
                e0, e1, e2, Win, bin, A, 1000);
            coagg_kernel<10><<<3000, 256, 0, stream>>>(
                A, iD0, iQ0, B, A, iD0, iQ0, B, 12000, 1);
            coagg_kernel<5><<<1500, 256, 0, stream>>>(
                B, iD1, iQ1, C, B, iD1, iQ1, C, 6000, 0);
            fc_out_kernel<<<750, 128, 0, stream>>>(
                C, Wout, bout, branchOut,
                C, Wout, bout, branchOut, 750);
        }
        mm128_kernel<<<1500, 128, 0, stream>>>(
            corO, Wc2s, P,
            simO, Ws2c, S, 750);
        integ2_kernel<<<1500, 128, 0, stream>>>(
            S, Wc2s, simO, P, outSim,
            P, Ws2c, corO, S, outCor, 750, a1, a2, b2);
    }
}